// Round 2
// baseline (350.306 us; speedup 1.0000x reference)
//
#include <hip/hip_runtime.h>

// ---- constants for this problem ----
// x: (81920, 256) f32 ; W_qkv: (256, 768) f32 ; W_proj: (256,256) f32 ; b_proj: (256,) f32
// B=4 batches, L=20480 rows/batch, H=8 heads, d=32, out: (81920,256) f32
#define M_ROWS 81920
#define KDIM 256
#define NQKV 768
#define LROWS 20480
#define EPSV 1e-6f
#define KV_CHUNKS 160   // chunks per batch; 128 rows each (4 tiles of 32)

using bf16x8 = __attribute__((ext_vector_type(8))) short;
using f32x4  = __attribute__((ext_vector_type(4))) float;

static __device__ __forceinline__ unsigned short f2bf(float f) {
  union { float f; unsigned int u; } c; c.f = f;
  unsigned int u = c.u;
  u += 0x7fff + ((u >> 16) & 1);   // round-to-nearest-even
  return (unsigned short)(u >> 16);
}
static __device__ __forceinline__ float bf2f(unsigned short h) {
  union { unsigned int u; float f; } c; c.u = ((unsigned int)h) << 16;
  return c.f;
}

// async global->LDS 16B copy (wave-uniform base + lane*16 LDS pattern required)
static __device__ __forceinline__ void async_cp16(const void* g, void* l) {
  __builtin_amdgcn_global_load_lds(
      (const __attribute__((address_space(1))) void*)(unsigned long long)g,
      (__attribute__((address_space(3))) void*)(unsigned int)(unsigned long long)l,
      16, 0, 0);
}

// ---------------- convert / transpose ----------------
__global__ void cvt_x(const float* __restrict__ x, unsigned short* __restrict__ xb) {
  long i = ((long)blockIdx.x * blockDim.x + threadIdx.x) * 4;
  float4 v = *(const float4*)(x + i);
  ushort4 o;
  o.x = f2bf(v.x); o.y = f2bf(v.y); o.z = f2bf(v.z); o.w = f2bf(v.w);
  *(ushort4*)(xb + i) = o;
}

__global__ void transpose_w(const float* __restrict__ w, unsigned short* __restrict__ wt,
                            int K, int N) {
  // w: K x N  ->  wt: N x K (bf16)
  int k = blockIdx.x;
  for (int n = threadIdx.x; n < N; n += blockDim.x)
    wt[(size_t)n * K + k] = f2bf(w[(size_t)k * N + n]);
}

// ---------------- bf16 MFMA GEMM, C = A @ Bt^T ----------------
// A: M x 256 bf16 row-major. Bt: N x 256 bf16 row-major.
// EPI==0: N=768, elu+1 on cols<512, store bf16 (qkv buffer)
// EPI==1: N=256, Bt batched per 20480 rows (Gt + nb*256*256), add bias, store f32
template <int EPI>
__global__ __launch_bounds__(256, 3)
void gemm_bt(const unsigned short* __restrict__ A,
             const unsigned short* __restrict__ Bt,
             void* __restrict__ C,
             const float* __restrict__ bias,
             int N) {
  __shared__ unsigned short As[128 * 32];
  __shared__ unsigned short Bs[128 * 32];
  const int K = 256;
  int t = threadIdx.x;
  int lane = t & 63;
  int w = t >> 6;
  int m0 = blockIdx.y * 128;
  int n0 = blockIdx.x * 128;
  const unsigned short* Bp = Bt;
  if (EPI == 1) Bp += (size_t)(blockIdx.y / 160) * 256 * 256;

  f32x4 acc[4][4];
#pragma unroll
  for (int i = 0; i < 4; i++)
#pragma unroll
    for (int j = 0; j < 4; j++) acc[i][j] = (f32x4){0.f, 0.f, 0.f, 0.f};

  int wm = w & 1, wn = w >> 1;
  int fm = lane & 15;
  int fk = (lane >> 4) * 8;
  int r0a = t >> 2, p0 = t & 3;          // chunk t
  int r1a = (t + 256) >> 2, p1 = t & 3;  // chunk t+256 (same low bits)

  for (int kt = 0; kt < 8; kt++) {
    int k0 = kt * 32;
    __syncthreads();
    async_cp16(A + (size_t)(m0 + r0a) * K + k0 + p0 * 8, As + (size_t)t * 8);
    async_cp16(A + (size_t)(m0 + r1a) * K + k0 + p1 * 8, As + (size_t)(t + 256) * 8);
    async_cp16(Bp + (size_t)(n0 + r0a) * K + k0 + p0 * 8, Bs + (size_t)t * 8);
    async_cp16(Bp + (size_t)(n0 + r1a) * K + k0 + p1 * 8, Bs + (size_t)(t + 256) * 8);
    __syncthreads();
    bf16x8 af[4], bfr[4];
#pragma unroll
    for (int i = 0; i < 4; i++)
      af[i] = *(const bf16x8*)(As + (wm * 64 + i * 16 + fm) * 32 + fk);
#pragma unroll
    for (int j = 0; j < 4; j++)
      bfr[j] = *(const bf16x8*)(Bs + (wn * 64 + j * 16 + fm) * 32 + fk);
#pragma unroll
    for (int i = 0; i < 4; i++)
#pragma unroll
      for (int j = 0; j < 4; j++)
        acc[i][j] = __builtin_amdgcn_mfma_f32_16x16x32_bf16(af[i], bfr[j], acc[i][j], 0, 0, 0);
  }

  int quad = lane >> 4;
  int col = lane & 15;
#pragma unroll
  for (int i = 0; i < 4; i++) {
#pragma unroll
    for (int j = 0; j < 4; j++) {
      int gm_base = m0 + wm * 64 + i * 16 + quad * 4;
      int gn = n0 + wn * 64 + j * 16 + col;
#pragma unroll
      for (int r = 0; r < 4; r++) {
        float v = acc[i][j][r];
        int gm = gm_base + r;
        if (EPI == 0) {
          if (gn < 512) v = (v > 0.f) ? v + 1.f : __expf(v);  // elu(v)+1
          ((unsigned short*)C)[(size_t)gm * N + gn] = f2bf(v);
        } else {
          ((float*)C)[(size_t)gm * N + gn] = v + bias[gn];
        }
      }
    }
  }
}

// ---------------- kv & k_sum partial reduction ----------------
// One block (512 thr = 8 waves) handles 128 rows x ALL 8 heads. k||v cols
// 256..767 are one contiguous 1024B run per row -> fully coalesced staging.
// Wave w = head w; lane accumulates a 4x4 outer-product patch.
// Partials (deterministic, no atomics): kvp[(n*KV_CHUNKS+chunk)*8+h][1056]
__global__ __launch_bounds__(512)
void kv_reduce(const unsigned short* __restrict__ qkv, float* __restrict__ kvp) {
  __shared__ unsigned short s[32 * 512];  // 32 rows x 512 el (k|v), 32 KB
  int chunk = blockIdx.x;                 // 0..KV_CHUNKS-1
  int n = blockIdx.y;
  int t = threadIdx.x;
  int lane = t & 63;
  int w = t >> 6;  // head
  long r0 = (long)n * LROWS + (long)chunk * 128;

  float acc[4][4] = {};
  float ks[4] = {};
  int mg = lane >> 3;
  int m0 = mg * 4, d0 = (lane & 7) * 4;

  for (int tile = 0; tile < 4; tile++) {
    __syncthreads();
#pragma unroll
    for (int q = 0; q < 4; q++) {
      int c = t + q * 512;            // chunk id 0..2047
      int row = c >> 6, part = c & 63;
      async_cp16(qkv + (size_t)(r0 + tile * 32 + row) * 768 + 256 + part * 8,
                 s + (size_t)c * 8);
    }
    __syncthreads();
#pragma unroll 4
    for (int row = 0; row < 32; row++) {
      ushort4 kk = *(const ushort4*)(s + row * 512 + w * 32 + d0);
      ushort4 vv = *(const ushort4*)(s + row * 512 + 256 + w * 32 + m0);
      float kf[4] = {bf2f(kk.x), bf2f(kk.y), bf2f(kk.z), bf2f(kk.w)};
      float vf[4] = {bf2f(vv.x), bf2f(vv.y), bf2f(vv.z), bf2f(vv.w)};
#pragma unroll
      for (int i = 0; i < 4; i++)
#pragma unroll
        for (int j = 0; j < 4; j++) acc[i][j] += vf[i] * kf[j];
      if (mg == 0) {
        ks[0] += kf[0]; ks[1] += kf[1]; ks[2] += kf[2]; ks[3] += kf[3];
      }
    }
  }
  float* o = kvp + ((size_t)(n * KV_CHUNKS + chunk) * 8 + w) * 1056;
#pragma unroll
  for (int i = 0; i < 4; i++)
#pragma unroll
    for (int j = 0; j < 4; j++) o[(m0 + i) * 32 + d0 + j] = acc[i][j];
  if (mg == 0) {
#pragma unroll
    for (int j = 0; j < 4; j++) o[1024 + d0 + j] = ks[j];
  }
}

// ---------------- combine partials -> kv (32x32 f32 per pair) + ksum ----------------
__global__ __launch_bounds__(256)
void kv_combine(const float* __restrict__ kvp, float* __restrict__ kv,
                float* __restrict__ ksum) {
  int pair = blockIdx.x;  // n*8+h
  int n = pair >> 3, h = pair & 7;
  int t = threadIdx.x;
  float a0 = 0.f, a1 = 0.f, a2 = 0.f, a3 = 0.f, a4 = 0.f;
  const float* base = kvp + ((size_t)(n * KV_CHUNKS) * 8 + h) * 1056;
  for (int c = 0; c < KV_CHUNKS; c++) {
    const float* p = base + (size_t)c * 8 * 1056;
    a0 += p[t]; a1 += p[t + 256]; a2 += p[t + 512]; a3 += p[t + 768];
    if (t < 32) a4 += p[1024 + t];
  }
  float* kvo = kv + (size_t)pair * 1024;
  kvo[t] = a0; kvo[t + 256] = a1; kvo[t + 512] = a2; kvo[t + 768] = a3;
  if (t < 32) ksum[pair * 32 + t] = a4;
}

// ---------------- fold kv into W_proj: Gt[n][c][h*32+d] = sum_m kv[n,h,m,d]*Wp[h*32+m][c]
__global__ __launch_bounds__(256)
void make_g(const float* __restrict__ kv, const float* __restrict__ wproj,
            unsigned short* __restrict__ gt) {
  __shared__ float kvs[1024];
  int pair = blockIdx.x;
  int n = pair >> 3, h = pair & 7;
  int c = threadIdx.x;
  for (int i = c; i < 1024; i += 256) kvs[i] = kv[(size_t)pair * 1024 + i];
  __syncthreads();
  float acc[32];
#pragma unroll
  for (int d = 0; d < 32; d++) acc[d] = 0.f;
  for (int m = 0; m < 32; m++) {
    float wp = wproj[(size_t)(h * 32 + m) * 256 + c];
#pragma unroll
    for (int d = 0; d < 32; d++) acc[d] += kvs[m * 32 + d] * wp;
  }
  unsigned short* o = gt + ((size_t)n * 256 + c) * 256 + h * 32;
#pragma unroll
  for (int d = 0; d < 32; d++) o[d] = f2bf(acc[d]);
}

// ---------------- per-row z and q' = z*q (bf16) ----------------
__global__ __launch_bounds__(256)
void scale_q(const unsigned short* __restrict__ qkv, const float* __restrict__ ksum,
             unsigned short* __restrict__ qp) {
  int t = threadIdx.x;
  int lane32 = t & 31;  // cols lane32*8 .. +7 (head = lane32/4)
  int rsub = t >> 5;    // 0..7
  long r0 = (long)blockIdx.x * 64;
  for (int p = 0; p < 8; p++) {
    long r = r0 + p * 8 + rsub;
    int n = (int)(r / LROWS);
    const unsigned short* q = qkv + r * 768 + lane32 * 8;
    ushort4 a = *(const ushort4*)(q);
    ushort4 b = *(const ushort4*)(q + 4);
    float qf[8] = {bf2f(a.x), bf2f(a.y), bf2f(a.z), bf2f(a.w),
                   bf2f(b.x), bf2f(b.y), bf2f(b.z), bf2f(b.w)};
    const float* ks = ksum + n * 256 + lane32 * 8;
    float sacc = 0.f;
#pragma unroll
    for (int i = 0; i < 8; i++) sacc += qf[i] * ks[i];
    sacc += __shfl_xor(sacc, 1);
    sacc += __shfl_xor(sacc, 2);
    float z = 1.f / (sacc + EPSV);
    ushort4 oa, ob;
    oa.x = f2bf(qf[0] * z); oa.y = f2bf(qf[1] * z);
    oa.z = f2bf(qf[2] * z); oa.w = f2bf(qf[3] * z);
    ob.x = f2bf(qf[4] * z); ob.y = f2bf(qf[5] * z);
    ob.z = f2bf(qf[6] * z); ob.w = f2bf(qf[7] * z);
    unsigned short* o = qp + r * 256 + lane32 * 8;
    *(ushort4*)o = oa;
    *(ushort4*)(o + 4) = ob;
  }
}

// ---------------- launch ----------------
extern "C" void kernel_launch(void* const* d_in, const int* in_sizes, int n_in,
                              void* d_out, int out_size, void* d_ws, size_t ws_size,
                              hipStream_t stream) {
  (void)in_sizes; (void)n_in; (void)out_size; (void)ws_size;
  const float* x = (const float*)d_in[0];
  const float* Wqkv = (const float*)d_in[1];
  const float* Wproj = (const float*)d_in[2];
  const float* bproj = (const float*)d_in[3];
  float* out = (float*)d_out;

  char* ws = (char*)d_ws;
  unsigned short* xbf    = (unsigned short*)(ws);             // 81920*256*2 = 41.9 MB
  // kvp reuses the xbf region (xbf is dead after gemm_bt<0>): 4*160*8*1056*4 = 21.6 MB
  float*          kvp    = (float*)(ws);
  unsigned short* wqkvt  = (unsigned short*)(ws + 41943040);  // 768*256*2
  unsigned short* qkv_bf = (unsigned short*)(ws + 42336256);  // 81920*768*2
  float*          kv     = (float*)(ws + 168165376);          // 32768*4
  float*          ksum   = (float*)(ws + 168296448);          // 1024*4
  unsigned short* gt     = (unsigned short*)(ws + 168300544); // 4*256*256*2
  unsigned short* qp     = (unsigned short*)(ws + 168824832); // 81920*256*2

  cvt_x<<<M_ROWS * KDIM / 1024, 256, 0, stream>>>(x, xbf);
  transpose_w<<<256, 256, 0, stream>>>(Wqkv, wqkvt, 256, 768);
  gemm_bt<0><<<dim3(NQKV / 128, M_ROWS / 128), 256, 0, stream>>>(xbf, wqkvt, qkv_bf, nullptr, NQKV);
  kv_reduce<<<dim3(KV_CHUNKS, 4), 512, 0, stream>>>(qkv_bf, kvp);
  kv_combine<<<32, 256, 0, stream>>>(kvp, kv, ksum);
  make_g<<<32, 256, 0, stream>>>(kv, Wproj, gt);
  scale_q<<<M_ROWS / 64, 256, 0, stream>>>(qkv_bf, ksum, qp);
  gemm_bt<1><<<dim3(2, M_ROWS / 128), 256, 0, stream>>>(qp, gt, out, bproj, 256);
}

// Round 3
// 332.002 us; speedup vs baseline: 1.0551x; 1.0551x over previous
//
#include <hip/hip_runtime.h>

// ---- constants for this problem ----
// x: (81920, 256) f32 ; W_qkv: (256, 768) f32 ; W_proj: (256,256) f32 ; b_proj: (256,) f32
// B=4 batches, L=20480 rows/batch, H=8 heads, d=32, out: (81920,256) f32
#define M_ROWS 81920
#define KDIM 256
#define NQKV 768
#define LROWS 20480
#define EPSV 1e-6f
#define KV_CHUNKS 160   // chunks per batch; 128 rows each (4 tiles of 32)

using bf16x8 = __attribute__((ext_vector_type(8))) short;
using f32x4  = __attribute__((ext_vector_type(4))) float;

static __device__ __forceinline__ unsigned short f2bf(float f) {
  union { float f; unsigned int u; } c; c.f = f;
  unsigned int u = c.u;
  u += 0x7fff + ((u >> 16) & 1);   // round-to-nearest-even
  return (unsigned short)(u >> 16);
}
static __device__ __forceinline__ float bf2f(unsigned short h) {
  union { unsigned int u; float f; } c; c.u = ((unsigned int)h) << 16;
  return c.f;
}

// async global->LDS 16B copy (wave-uniform base + lane*16 LDS pattern required)
static __device__ __forceinline__ void async_cp16(const void* g, void* l) {
  __builtin_amdgcn_global_load_lds(
      (const __attribute__((address_space(1))) void*)(unsigned long long)g,
      (__attribute__((address_space(3))) void*)(unsigned int)(unsigned long long)l,
      16, 0, 0);
}

// ---------------- convert / transpose ----------------
__global__ void cvt_x(const float* __restrict__ x, unsigned short* __restrict__ xb) {
  long i = ((long)blockIdx.x * blockDim.x + threadIdx.x) * 4;
  float4 v = *(const float4*)(x + i);
  ushort4 o;
  o.x = f2bf(v.x); o.y = f2bf(v.y); o.z = f2bf(v.z); o.w = f2bf(v.w);
  *(ushort4*)(xb + i) = o;
}

// w: 256 x 768 f32 -> wt: 768 x 256 bf16, LDS-tiled (coalesced both sides)
__global__ __launch_bounds__(256)
void transpose_w(const float* __restrict__ w, unsigned short* __restrict__ wt) {
  __shared__ unsigned short lds[64][258];
  int n0 = blockIdx.x * 64;
  int t = threadIdx.x;
#pragma unroll 4
  for (int it = 0; it < 64; it++) {
    int k = (t >> 6) + 4 * it;
    int n = t & 63;
    lds[n][k] = f2bf(w[(size_t)k * NQKV + n0 + n]);
  }
  __syncthreads();
#pragma unroll
  for (int it = 0; it < 16; it++) {
    int idx = it * 256 + t;
    int n = idx >> 6, c4 = (idx & 63) * 4;
    ushort4 v;
    v.x = lds[n][c4]; v.y = lds[n][c4 + 1]; v.z = lds[n][c4 + 2]; v.w = lds[n][c4 + 3];
    *(ushort4*)(wt + (size_t)(n0 + n) * 256 + c4) = v;
  }
}

// ---------------- bf16 MFMA GEMM, C = A @ Bt^T ----------------
// A: M x 256 bf16 row-major. Bt: N x 256 bf16 row-major.
// 1D grid, XCD-swizzled: xcd = id&7 owns contiguous m-range (80 m-tiles),
// iterating all n-tiles per m-tile -> A-tile fetched once per XCD L2.
// LDS layout permuted so fragment reads are ds_read_b128 @ base+lane*16
// (conflict-free): slot(row,p) = (row>>4)*64 + p*16 + (row&15).
// EPI==0: N=768 (6 n-tiles), elu+1 on cols<512, store bf16 (qkv buffer)
// EPI==1: N=256 (2 n-tiles), Bt batched per 160 m-tiles, add bias, store f32
template <int EPI>
__global__ __launch_bounds__(256, 3)
void gemm_bt(const unsigned short* __restrict__ A,
             const unsigned short* __restrict__ Bt,
             void* __restrict__ C,
             const float* __restrict__ bias) {
  __shared__ unsigned short As[128 * 32];
  __shared__ unsigned short Bs[128 * 32];
  const int K = 256;
  const int N = (EPI == 0) ? NQKV : 256;
  const int NT = (EPI == 0) ? 6 : 2;
  int t = threadIdx.x;
  int lane = t & 63;
  int w = t >> 6;

  int id = blockIdx.x;
  int xcd = id & 7;
  int local = id >> 3;
  int mt = local / NT;
  int nt = local - mt * NT;
  int mtile = xcd * 80 + mt;
  int m0 = mtile * 128;
  int n0 = nt * 128;
  const unsigned short* Bp = Bt;
  if (EPI == 1) Bp += (size_t)(mtile / 160) * 256 * 256;

  f32x4 acc[4][4];
#pragma unroll
  for (int i = 0; i < 4; i++)
#pragma unroll
    for (int j = 0; j < 4; j++) acc[i][j] = (f32x4){0.f, 0.f, 0.f, 0.f};

  int wm = w & 1, wn = w >> 1;
  int fm_s = lane & 15;   // staging: row-in-group
  int p_s = lane >> 4;    // staging: k-quarter

  for (int kt = 0; kt < 8; kt++) {
    int k0 = kt * 32;
    __syncthreads();
#pragma unroll
    for (int q = 0; q < 2; q++) {
      int g = w * 2 + q;
      int row = g * 16 + fm_s;
      async_cp16(A + (size_t)(m0 + row) * K + k0 + p_s * 8, As + (size_t)(g * 64 + lane) * 8);
      async_cp16(Bp + (size_t)(n0 + row) * K + k0 + p_s * 8, Bs + (size_t)(g * 64 + lane) * 8);
    }
    __syncthreads();
    bf16x8 af[4], bfr[4];
#pragma unroll
    for (int i = 0; i < 4; i++)
      af[i] = *(const bf16x8*)(As + (size_t)((i + 4 * wm) * 64 + lane) * 8);
#pragma unroll
    for (int j = 0; j < 4; j++)
      bfr[j] = *(const bf16x8*)(Bs + (size_t)((j + 4 * wn) * 64 + lane) * 8);
#pragma unroll
    for (int i = 0; i < 4; i++)
#pragma unroll
      for (int j = 0; j < 4; j++)
        acc[i][j] = __builtin_amdgcn_mfma_f32_16x16x32_bf16(af[i], bfr[j], acc[i][j], 0, 0, 0);
  }

  int quad = lane >> 4;
  int col = lane & 15;
#pragma unroll
  for (int i = 0; i < 4; i++) {
#pragma unroll
    for (int j = 0; j < 4; j++) {
      int gm_base = m0 + wm * 64 + i * 16 + quad * 4;
      int gn = n0 + wn * 64 + j * 16 + col;
#pragma unroll
      for (int r = 0; r < 4; r++) {
        float v = acc[i][j][r];
        int gm = gm_base + r;
        if (EPI == 0) {
          if (gn < 512) v = (v > 0.f) ? v + 1.f : __expf(v);  // elu(v)+1
          ((unsigned short*)C)[(size_t)gm * N + gn] = f2bf(v);
        } else {
          ((float*)C)[(size_t)gm * N + gn] = v + bias[gn];
        }
      }
    }
  }
}

// ---------------- kv & k_sum partial reduction ----------------
// One block (512 thr = 8 waves) handles 128 rows x ALL 8 heads. k||v cols
// 256..767 are one contiguous 1024B run per row -> fully coalesced staging.
// Wave w = head w; lane accumulates a 4x4 outer-product patch.
// Partials (deterministic, no atomics): kvp[(n*KV_CHUNKS+chunk)*8+h][1056]
__global__ __launch_bounds__(512)
void kv_reduce(const unsigned short* __restrict__ qkv, float* __restrict__ kvp) {
  __shared__ unsigned short s[32 * 512];  // 32 rows x 512 el (k|v), 32 KB
  int chunk = blockIdx.x;                 // 0..KV_CHUNKS-1
  int n = blockIdx.y;
  int t = threadIdx.x;
  int lane = t & 63;
  int w = t >> 6;  // head
  long r0 = (long)n * LROWS + (long)chunk * 128;

  float acc[4][4] = {};
  float ks[4] = {};
  int mg = lane >> 3;
  int m0 = mg * 4, d0 = (lane & 7) * 4;

  for (int tile = 0; tile < 4; tile++) {
    __syncthreads();
#pragma unroll
    for (int q = 0; q < 4; q++) {
      int c = t + q * 512;            // chunk id 0..2047
      int row = c >> 6, part = c & 63;
      async_cp16(qkv + (size_t)(r0 + tile * 32 + row) * 768 + 256 + part * 8,
                 s + (size_t)c * 8);
    }
    __syncthreads();
#pragma unroll 4
    for (int row = 0; row < 32; row++) {
      ushort4 kk = *(const ushort4*)(s + row * 512 + w * 32 + d0);
      ushort4 vv = *(const ushort4*)(s + row * 512 + 256 + w * 32 + m0);
      float kf[4] = {bf2f(kk.x), bf2f(kk.y), bf2f(kk.z), bf2f(kk.w)};
      float vf[4] = {bf2f(vv.x), bf2f(vv.y), bf2f(vv.z), bf2f(vv.w)};
#pragma unroll
      for (int i = 0; i < 4; i++)
#pragma unroll
        for (int j = 0; j < 4; j++) acc[i][j] += vf[i] * kf[j];
      if (mg == 0) {
        ks[0] += kf[0]; ks[1] += kf[1]; ks[2] += kf[2]; ks[3] += kf[3];
      }
    }
  }
  float* o = kvp + ((size_t)(n * KV_CHUNKS + chunk) * 8 + w) * 1056;
#pragma unroll
  for (int i = 0; i < 4; i++)
#pragma unroll
    for (int j = 0; j < 4; j++) o[(m0 + i) * 32 + d0 + j] = acc[i][j];
  if (mg == 0) {
#pragma unroll
    for (int j = 0; j < 4; j++) o[1024 + d0 + j] = ks[j];
  }
}

// ---------------- combine partials, stage 1: 160 chunks -> 8 per pair ----------------
__global__ __launch_bounds__(256)
void kv_combine1(const float* __restrict__ kvp, float* __restrict__ kvp2) {
  int b = blockIdx.x;        // pair*8 + o
  int pair = b >> 3, o = b & 7;
  int n = pair >> 3, h = pair & 7;
  int t = threadIdx.x;
  float a0 = 0.f, a1 = 0.f, a2 = 0.f, a3 = 0.f, a4 = 0.f;
  const float* base = kvp + ((size_t)(n * KV_CHUNKS) * 8 + h) * 1056;
  for (int j = 0; j < KV_CHUNKS / 8; j++) {
    const float* p = base + (size_t)(o + 8 * j) * 8 * 1056;
    a0 += p[t]; a1 += p[t + 256]; a2 += p[t + 512]; a3 += p[t + 768];
    if (t < 32) a4 += p[1024 + t];
  }
  float* oo = kvp2 + (size_t)b * 1056;
  oo[t] = a0; oo[t + 256] = a1; oo[t + 512] = a2; oo[t + 768] = a3;
  if (t < 32) oo[1024 + t] = a4;
}

// ---------------- combine partials, stage 2: 8 -> kv + ksum ----------------
__global__ __launch_bounds__(256)
void kv_combine2(const float* __restrict__ kvp2, float* __restrict__ kv,
                 float* __restrict__ ksum) {
  int pair = blockIdx.x;
  int t = threadIdx.x;
  float a0 = 0.f, a1 = 0.f, a2 = 0.f, a3 = 0.f, a4 = 0.f;
  const float* base = kvp2 + (size_t)pair * 8 * 1056;
#pragma unroll
  for (int s = 0; s < 8; s++) {
    const float* p = base + (size_t)s * 1056;
    a0 += p[t]; a1 += p[t + 256]; a2 += p[t + 512]; a3 += p[t + 768];
    if (t < 32) a4 += p[1024 + t];
  }
  float* kvo = kv + (size_t)pair * 1024;
  kvo[t] = a0; kvo[t + 256] = a1; kvo[t + 512] = a2; kvo[t + 768] = a3;
  if (t < 32) ksum[pair * 32 + t] = a4;
}

// ---------------- fold kv into W_proj: Gt[n][c][h*32+d] = sum_m kv[n,h,m,d]*Wp[h*32+m][c]
__global__ __launch_bounds__(256)
void make_g(const float* __restrict__ kv, const float* __restrict__ wproj,
            unsigned short* __restrict__ gt) {
  __shared__ float kvs[1024];
  int pair = blockIdx.x;
  int n = pair >> 3, h = pair & 7;
  int c = threadIdx.x;
  for (int i = c; i < 1024; i += 256) kvs[i] = kv[(size_t)pair * 1024 + i];
  __syncthreads();
  float acc[32];
#pragma unroll
  for (int d = 0; d < 32; d++) acc[d] = 0.f;
  for (int m = 0; m < 32; m++) {
    float wp = wproj[(size_t)(h * 32 + m) * 256 + c];
#pragma unroll
    for (int d = 0; d < 32; d++) acc[d] += kvs[m * 32 + d] * wp;
  }
  unsigned short* o = gt + ((size_t)n * 256 + c) * 256 + h * 32;
#pragma unroll
  for (int d = 0; d < 32; d++) o[d] = f2bf(acc[d]);
}

// ---------------- per-row z and q' = z*q (bf16) ----------------
__global__ __launch_bounds__(256)
void scale_q(const unsigned short* __restrict__ qkv, const float* __restrict__ ksum,
             unsigned short* __restrict__ qp) {
  int t = threadIdx.x;
  int lane32 = t & 31;  // cols lane32*8 .. +7 (head = lane32/4)
  int rsub = t >> 5;    // 0..7
  long r0 = (long)blockIdx.x * 64;
  for (int p = 0; p < 8; p++) {
    long r = r0 + p * 8 + rsub;
    int n = (int)(r / LROWS);
    const unsigned short* q = qkv + r * 768 + lane32 * 8;
    ushort4 a = *(const ushort4*)(q);
    ushort4 b = *(const ushort4*)(q + 4);
    float qf[8] = {bf2f(a.x), bf2f(a.y), bf2f(a.z), bf2f(a.w),
                   bf2f(b.x), bf2f(b.y), bf2f(b.z), bf2f(b.w)};
    const float* ks = ksum + n * 256 + lane32 * 8;
    float sacc = 0.f;
#pragma unroll
    for (int i = 0; i < 8; i++) sacc += qf[i] * ks[i];
    sacc += __shfl_xor(sacc, 1);
    sacc += __shfl_xor(sacc, 2);
    float z = 1.f / (sacc + EPSV);
    ushort4 oa, ob;
    oa.x = f2bf(qf[0] * z); oa.y = f2bf(qf[1] * z);
    oa.z = f2bf(qf[2] * z); oa.w = f2bf(qf[3] * z);
    ob.x = f2bf(qf[4] * z); ob.y = f2bf(qf[5] * z);
    ob.z = f2bf(qf[6] * z); ob.w = f2bf(qf[7] * z);
    unsigned short* o = qp + r * 256 + lane32 * 8;
    *(ushort4*)o = oa;
    *(ushort4*)(o + 4) = ob;
  }
}

// ---------------- launch ----------------
extern "C" void kernel_launch(void* const* d_in, const int* in_sizes, int n_in,
                              void* d_out, int out_size, void* d_ws, size_t ws_size,
                              hipStream_t stream) {
  (void)in_sizes; (void)n_in; (void)out_size; (void)ws_size;
  const float* x = (const float*)d_in[0];
  const float* Wqkv = (const float*)d_in[1];
  const float* Wproj = (const float*)d_in[2];
  const float* bproj = (const float*)d_in[3];
  float* out = (float*)d_out;

  char* ws = (char*)d_ws;
  unsigned short* xbf    = (unsigned short*)(ws);             // 81920*256*2 = 41.9 MB
  // kvp / kvp2 reuse the xbf region (xbf dead after gemm_bt<0>):
  float*          kvp    = (float*)(ws);                      // 4*160*8*1056*4 = 21.6 MB
  float*          kvp2   = (float*)(ws + 33554432);           // 256*1056*4 = 1.08 MB
  unsigned short* wqkvt  = (unsigned short*)(ws + 41943040);  // 768*256*2
  unsigned short* qkv_bf = (unsigned short*)(ws + 42336256);  // 81920*768*2
  float*          kv     = (float*)(ws + 168165376);          // 32768*4
  float*          ksum   = (float*)(ws + 168296448);          // 1024*4
  unsigned short* gt     = (unsigned short*)(ws + 168300544); // 4*256*256*2
  unsigned short* qp     = (unsigned short*)(ws + 168824832); // 81920*256*2

  cvt_x<<<M_ROWS * KDIM / 1024, 256, 0, stream>>>(x, xbf);
  transpose_w<<<NQKV / 64, 256, 0, stream>>>(Wqkv, wqkvt);
  gemm_bt<0><<<3840, 256, 0, stream>>>(xbf, wqkvt, qkv_bf, nullptr);
  kv_reduce<<<dim3(KV_CHUNKS, 4), 512, 0, stream>>>(qkv_bf, kvp);
  kv_combine1<<<256, 256, 0, stream>>>(kvp, kvp2);
  kv_combine2<<<32, 256, 0, stream>>>(kvp2, kv, ksum);
  make_g<<<32, 256, 0, stream>>>(kv, Wproj, gt);
  scale_q<<<M_ROWS / 64, 256, 0, stream>>>(qkv_bf, ksum, qp);
  gemm_bt<1><<<1280, 256, 0, stream>>>(qp, gt, out, bproj);
}

// Round 4
// 313.453 us; speedup vs baseline: 1.1176x; 1.0592x over previous
//
#include <hip/hip_runtime.h>

// ---- constants for this problem ----
// x: (81920, 256) f32 ; W_qkv: (256, 768) f32 ; W_proj: (256,256) f32 ; b_proj: (256,) f32
// B=4 batches, L=20480 rows/batch, H=8 heads, d=32, out: (81920,256) f32
#define M_ROWS 81920
#define KDIM 256
#define NQKV 768
#define LROWS 20480
#define EPSV 1e-6f
#define KV_CHUNKS 160   // chunks per batch; 128 rows each (4 tiles of 32)

using bf16x8 = __attribute__((ext_vector_type(8))) short;
using f32x4  = __attribute__((ext_vector_type(4))) float;

static __device__ __forceinline__ unsigned short f2bf(float f) {
  union { float f; unsigned int u; } c; c.f = f;
  unsigned int u = c.u;
  u += 0x7fff + ((u >> 16) & 1);   // round-to-nearest-even
  return (unsigned short)(u >> 16);
}
static __device__ __forceinline__ float bf2f(unsigned short h) {
  union { unsigned int u; float f; } c; c.u = ((unsigned int)h) << 16;
  return c.f;
}

// async global->LDS 16B copy (wave-uniform base + lane*16 LDS pattern required)
static __device__ __forceinline__ void async_cp16(const void* g, void* l) {
  __builtin_amdgcn_global_load_lds(
      (const __attribute__((address_space(1))) void*)(unsigned long long)g,
      (__attribute__((address_space(3))) void*)(unsigned int)(unsigned long long)l,
      16, 0, 0);
}

// ---------------- convert / transpose ----------------
__global__ void cvt_x(const float* __restrict__ x, unsigned short* __restrict__ xb) {
  long i = ((long)blockIdx.x * blockDim.x + threadIdx.x) * 4;
  float4 v = *(const float4*)(x + i);
  ushort4 o;
  o.x = f2bf(v.x); o.y = f2bf(v.y); o.z = f2bf(v.z); o.w = f2bf(v.w);
  *(ushort4*)(xb + i) = o;
}

// w: 256 x 768 f32 -> wt: 768 x 256 bf16, LDS-tiled (coalesced both sides)
__global__ __launch_bounds__(256)
void transpose_w(const float* __restrict__ w, unsigned short* __restrict__ wt) {
  __shared__ unsigned short lds[64][258];
  int n0 = blockIdx.x * 64;
  int t = threadIdx.x;
#pragma unroll 4
  for (int it = 0; it < 64; it++) {
    int k = (t >> 6) + 4 * it;
    int n = t & 63;
    lds[n][k] = f2bf(w[(size_t)k * NQKV + n0 + n]);
  }
  __syncthreads();
#pragma unroll
  for (int it = 0; it < 16; it++) {
    int idx = it * 256 + t;
    int n = idx >> 6, c4 = (idx & 63) * 4;
    ushort4 v;
    v.x = lds[n][c4]; v.y = lds[n][c4 + 1]; v.z = lds[n][c4 + 2]; v.w = lds[n][c4 + 3];
    *(ushort4*)(wt + (size_t)(n0 + n) * 256 + c4) = v;
  }
}

// ---------------- bf16 MFMA GEMM, C = A @ Bt^T ----------------
// A: M x 256 bf16 row-major. Bt: N x 256 bf16 row-major.
// 1D grid, XCD-swizzled: xcd = id&7 owns contiguous m-range (80 m-tiles).
// Staging: lane c loads (row c>>2, quarter (c&3)^((c>>4)&3)) -> 4 consecutive
// lanes cover one contiguous 64B row-chunk (coalesced) AND the induced LDS
// layout gives conflict-free ds_read_b128 fragment reads.
// MFMA operands SWAPPED: acc[i][j] = mfma(b[j], a[i]) -> quad-side = n,
// lane-side = m -> each lane holds 4 CONSECUTIVE n per reg -> packed stores.
// EPI==0: N=768 (6 n-tiles), elu+1 on cols<512, store bf16 x4 (8B)
// EPI==1: N=256 (2 n-tiles), Bt batched per 160 m-tiles, +bias, f32x4 (16B)
template <int EPI>
__global__ __launch_bounds__(256, 3)
void gemm_bt(const unsigned short* __restrict__ A,
             const unsigned short* __restrict__ Bt,
             void* __restrict__ C,
             const float* __restrict__ bias) {
  __shared__ unsigned short As[128 * 32];
  __shared__ unsigned short Bs[128 * 32];
  const int K = 256;
  const int N = (EPI == 0) ? NQKV : 256;
  const int NT = (EPI == 0) ? 6 : 2;
  int t = threadIdx.x;
  int lane = t & 63;
  int w = t >> 6;

  int id = blockIdx.x;
  int xcd = id & 7;
  int local = id >> 3;
  int mt = local / NT;
  int nt = local - mt * NT;
  int mtile = xcd * 80 + mt;
  int m0 = mtile * 128;
  int n0 = nt * 128;
  const unsigned short* Bp = Bt;
  if (EPI == 1) Bp += (size_t)(mtile / 160) * 256 * 256;

  f32x4 acc[4][4];
#pragma unroll
  for (int i = 0; i < 4; i++)
#pragma unroll
    for (int j = 0; j < 4; j++) acc[i][j] = (f32x4){0.f, 0.f, 0.f, 0.f};

  int wm = w & 1, wn = w >> 1;
  int fm = lane & 15;
  int fq = lane >> 4;
  int xr = (fm >> 2) & 3;  // fragment-read XOR key

  // staging chunks c0 = t, c1 = t + 256 (p1 == p0 since 256>>4 ≡ 0 mod 4)
  int sr0 = t >> 2, sp = (t & 3) ^ ((t >> 4) & 3);
  int sr1 = sr0 + 64;

  for (int kt = 0; kt < 8; kt++) {
    int k0 = kt * 32;
    __syncthreads();
    async_cp16(A + (size_t)(m0 + sr0) * K + k0 + sp * 8, As + (size_t)t * 8);
    async_cp16(A + (size_t)(m0 + sr1) * K + k0 + sp * 8, As + (size_t)(t + 256) * 8);
    async_cp16(Bp + (size_t)(n0 + sr0) * K + k0 + sp * 8, Bs + (size_t)t * 8);
    async_cp16(Bp + (size_t)(n0 + sr1) * K + k0 + sp * 8, Bs + (size_t)(t + 256) * 8);
    __syncthreads();
    bf16x8 af[4], bfr[4];
#pragma unroll
    for (int i = 0; i < 4; i++) {
      int row = wm * 64 + i * 16 + fm;
      af[i] = *(const bf16x8*)(As + (size_t)(row * 4 + (fq ^ xr)) * 8);
    }
#pragma unroll
    for (int j = 0; j < 4; j++) {
      int row = wn * 64 + j * 16 + fm;
      bfr[j] = *(const bf16x8*)(Bs + (size_t)(row * 4 + (fq ^ xr)) * 8);
    }
#pragma unroll
    for (int i = 0; i < 4; i++)
#pragma unroll
      for (int j = 0; j < 4; j++)
        acc[i][j] = __builtin_amdgcn_mfma_f32_16x16x32_bf16(bfr[j], af[i], acc[i][j], 0, 0, 0);
  }

  // epilogue: m = m0 + wm*64 + i*16 + fm ; n = n0 + wn*64 + j*16 + fq*4 + r
#pragma unroll
  for (int i = 0; i < 4; i++) {
    int gm = m0 + wm * 64 + i * 16 + fm;
#pragma unroll
    for (int j = 0; j < 4; j++) {
      int gnb = n0 + wn * 64 + j * 16 + fq * 4;
      if (EPI == 0) {
        float v0 = acc[i][j][0], v1 = acc[i][j][1], v2 = acc[i][j][2], v3 = acc[i][j][3];
        if (gnb < 512) {  // elu+1 on q,k columns (uniform over the 4-pack)
          v0 = (v0 > 0.f) ? v0 + 1.f : __expf(v0);
          v1 = (v1 > 0.f) ? v1 + 1.f : __expf(v1);
          v2 = (v2 > 0.f) ? v2 + 1.f : __expf(v2);
          v3 = (v3 > 0.f) ? v3 + 1.f : __expf(v3);
        }
        ushort4 pk;
        pk.x = f2bf(v0); pk.y = f2bf(v1); pk.z = f2bf(v2); pk.w = f2bf(v3);
        *(ushort4*)((unsigned short*)C + (size_t)gm * N + gnb) = pk;
      } else {
        float4 bi = *(const float4*)(bias + gnb);
        float4 o;
        o.x = acc[i][j][0] + bi.x; o.y = acc[i][j][1] + bi.y;
        o.z = acc[i][j][2] + bi.z; o.w = acc[i][j][3] + bi.w;
        *(float4*)((float*)C + (size_t)gm * N + gnb) = o;
      }
    }
  }
}

// ---------------- kv & k_sum partial reduction ----------------
// One block (512 thr = 8 waves) handles 128 rows x ALL 8 heads. k||v cols
// 256..767 are one contiguous 1024B run per row -> fully coalesced staging.
// Wave w = head w; lane accumulates a 4x4 outer-product patch.
// Partials (deterministic, no atomics): kvp[(n*KV_CHUNKS+chunk)*8+h][1056]
__global__ __launch_bounds__(512)
void kv_reduce(const unsigned short* __restrict__ qkv, float* __restrict__ kvp) {
  __shared__ unsigned short s[32 * 512];  // 32 rows x 512 el (k|v), 32 KB
  int chunk = blockIdx.x;                 // 0..KV_CHUNKS-1
  int n = blockIdx.y;
  int t = threadIdx.x;
  int lane = t & 63;
  int w = t >> 6;  // head
  long r0 = (long)n * LROWS + (long)chunk * 128;

  float acc[4][4] = {};
  float ks[4] = {};
  int mg = lane >> 3;
  int m0 = mg * 4, d0 = (lane & 7) * 4;

  for (int tile = 0; tile < 4; tile++) {
    __syncthreads();
#pragma unroll
    for (int q = 0; q < 4; q++) {
      int c = t + q * 512;            // chunk id 0..2047
      int row = c >> 6, part = c & 63;
      async_cp16(qkv + (size_t)(r0 + tile * 32 + row) * 768 + 256 + part * 8,
                 s + (size_t)c * 8);
    }
    __syncthreads();
#pragma unroll 4
    for (int row = 0; row < 32; row++) {
      ushort4 kk = *(const ushort4*)(s + row * 512 + w * 32 + d0);
      ushort4 vv = *(const ushort4*)(s + row * 512 + 256 + w * 32 + m0);
      float kf[4] = {bf2f(kk.x), bf2f(kk.y), bf2f(kk.z), bf2f(kk.w)};
      float vf[4] = {bf2f(vv.x), bf2f(vv.y), bf2f(vv.z), bf2f(vv.w)};
#pragma unroll
      for (int i = 0; i < 4; i++)
#pragma unroll
        for (int j = 0; j < 4; j++) acc[i][j] += vf[i] * kf[j];
      if (mg == 0) {
        ks[0] += kf[0]; ks[1] += kf[1]; ks[2] += kf[2]; ks[3] += kf[3];
      }
    }
  }
  float* o = kvp + ((size_t)(n * KV_CHUNKS + chunk) * 8 + w) * 1056;
#pragma unroll
  for (int i = 0; i < 4; i++)
#pragma unroll
    for (int j = 0; j < 4; j++) o[(m0 + i) * 32 + d0 + j] = acc[i][j];
  if (mg == 0) {
#pragma unroll
    for (int j = 0; j < 4; j++) o[1024 + d0 + j] = ks[j];
  }
}

// ---------------- combine partials, stage 1: 160 chunks -> 8 per pair ----------------
__global__ __launch_bounds__(256)
void kv_combine1(const float* __restrict__ kvp, float* __restrict__ kvp2) {
  int b = blockIdx.x;        // pair*8 + o
  int pair = b >> 3, o = b & 7;
  int n = pair >> 3, h = pair & 7;
  int t = threadIdx.x;
  float a0 = 0.f, a1 = 0.f, a2 = 0.f, a3 = 0.f, a4 = 0.f;
  const float* base = kvp + ((size_t)(n * KV_CHUNKS) * 8 + h) * 1056;
  for (int j = 0; j < KV_CHUNKS / 8; j++) {
    const float* p = base + (size_t)(o + 8 * j) * 8 * 1056;
    a0 += p[t]; a1 += p[t + 256]; a2 += p[t + 512]; a3 += p[t + 768];
    if (t < 32) a4 += p[1024 + t];
  }
  float* oo = kvp2 + (size_t)b * 1056;
  oo[t] = a0; oo[t + 256] = a1; oo[t + 512] = a2; oo[t + 768] = a3;
  if (t < 32) oo[1024 + t] = a4;
}

// ---------------- combine partials, stage 2: 8 -> kv + ksum ----------------
__global__ __launch_bounds__(256)
void kv_combine2(const float* __restrict__ kvp2, float* __restrict__ kv,
                 float* __restrict__ ksum) {
  int pair = blockIdx.x;
  int t = threadIdx.x;
  float a0 = 0.f, a1 = 0.f, a2 = 0.f, a3 = 0.f, a4 = 0.f;
  const float* base = kvp2 + (size_t)pair * 8 * 1056;
#pragma unroll
  for (int s = 0; s < 8; s++) {
    const float* p = base + (size_t)s * 1056;
    a0 += p[t]; a1 += p[t + 256]; a2 += p[t + 512]; a3 += p[t + 768];
    if (t < 32) a4 += p[1024 + t];
  }
  float* kvo = kv + (size_t)pair * 1024;
  kvo[t] = a0; kvo[t + 256] = a1; kvo[t + 512] = a2; kvo[t + 768] = a3;
  if (t < 32) ksum[pair * 32 + t] = a4;
}

// ---------------- fold kv into W_proj: Gt[n][c][h*32+d] = sum_m kv[n,h,m,d]*Wp[h*32+m][c]
__global__ __launch_bounds__(256)
void make_g(const float* __restrict__ kv, const float* __restrict__ wproj,
            unsigned short* __restrict__ gt) {
  __shared__ float kvs[1024];
  int pair = blockIdx.x;
  int n = pair >> 3, h = pair & 7;
  int c = threadIdx.x;
  for (int i = c; i < 1024; i += 256) kvs[i] = kv[(size_t)pair * 1024 + i];
  __syncthreads();
  float acc[32];
#pragma unroll
  for (int d = 0; d < 32; d++) acc[d] = 0.f;
  for (int m = 0; m < 32; m++) {
    float wp = wproj[(size_t)(h * 32 + m) * 256 + c];
#pragma unroll
    for (int d = 0; d < 32; d++) acc[d] += kvs[m * 32 + d] * wp;
  }
  unsigned short* o = gt + ((size_t)n * 256 + c) * 256 + h * 32;
#pragma unroll
  for (int d = 0; d < 32; d++) o[d] = f2bf(acc[d]);
}

// ---------------- per-row z and q' = z*q (bf16) ----------------
__global__ __launch_bounds__(256)
void scale_q(const unsigned short* __restrict__ qkv, const float* __restrict__ ksum,
             unsigned short* __restrict__ qp) {
  int t = threadIdx.x;
  int lane32 = t & 31;  // cols lane32*8 .. +7 (head = lane32/4)
  int rsub = t >> 5;    // 0..7
  long r0 = (long)blockIdx.x * 64;
  for (int p = 0; p < 8; p++) {
    long r = r0 + p * 8 + rsub;
    int n = (int)(r / LROWS);
    const unsigned short* q = qkv + r * 768 + lane32 * 8;
    ushort4 a = *(const ushort4*)(q);
    ushort4 b = *(const ushort4*)(q + 4);
    float qf[8] = {bf2f(a.x), bf2f(a.y), bf2f(a.z), bf2f(a.w),
                   bf2f(b.x), bf2f(b.y), bf2f(b.z), bf2f(b.w)};
    const float* ks = ksum + n * 256 + lane32 * 8;
    float sacc = 0.f;
#pragma unroll
    for (int i = 0; i < 8; i++) sacc += qf[i] * ks[i];
    sacc += __shfl_xor(sacc, 1);
    sacc += __shfl_xor(sacc, 2);
    float z = 1.f / (sacc + EPSV);
    ushort4 oa, ob;
    oa.x = f2bf(qf[0] * z); oa.y = f2bf(qf[1] * z);
    oa.z = f2bf(qf[2] * z); oa.w = f2bf(qf[3] * z);
    ob.x = f2bf(qf[4] * z); ob.y = f2bf(qf[5] * z);
    ob.z = f2bf(qf[6] * z); ob.w = f2bf(qf[7] * z);
    unsigned short* o = qp + r * 256 + lane32 * 8;
    *(ushort4*)o = oa;
    *(ushort4*)(o + 4) = ob;
  }
}

// ---------------- launch ----------------
extern "C" void kernel_launch(void* const* d_in, const int* in_sizes, int n_in,
                              void* d_out, int out_size, void* d_ws, size_t ws_size,
                              hipStream_t stream) {
  (void)in_sizes; (void)n_in; (void)out_size; (void)ws_size;
  const float* x = (const float*)d_in[0];
  const float* Wqkv = (const float*)d_in[1];
  const float* Wproj = (const float*)d_in[2];
  const float* bproj = (const float*)d_in[3];
  float* out = (float*)d_out;

  char* ws = (char*)d_ws;
  unsigned short* xbf    = (unsigned short*)(ws);             // 81920*256*2 = 41.9 MB
  // kvp / kvp2 reuse the xbf region (xbf dead after gemm_bt<0>):
  float*          kvp    = (float*)(ws);                      // 4*160*8*1056*4 = 21.6 MB
  float*          kvp2   = (float*)(ws + 33554432);           // 256*1056*4 = 1.08 MB
  unsigned short* wqkvt  = (unsigned short*)(ws + 41943040);  // 768*256*2
  unsigned short* qkv_bf = (unsigned short*)(ws + 42336256);  // 81920*768*2
  float*          kv     = (float*)(ws + 168165376);          // 32768*4
  float*          ksum   = (float*)(ws + 168296448);          // 1024*4
  unsigned short* gt     = (unsigned short*)(ws + 168300544); // 4*256*256*2
  unsigned short* qp     = (unsigned short*)(ws + 168824832); // 81920*256*2

  cvt_x<<<M_ROWS * KDIM / 1024, 256, 0, stream>>>(x, xbf);
  transpose_w<<<NQKV / 64, 256, 0, stream>>>(Wqkv, wqkvt);
  gemm_bt<0><<<3840, 256, 0, stream>>>(xbf, wqkvt, qkv_bf, nullptr);
  kv_reduce<<<dim3(KV_CHUNKS, 4), 512, 0, stream>>>(qkv_bf, kvp);
  kv_combine1<<<256, 256, 0, stream>>>(kvp, kvp2);
  kv_combine2<<<32, 256, 0, stream>>>(kvp2, kv, ksum);
  make_g<<<32, 256, 0, stream>>>(kv, Wproj, gt);
  scale_q<<<M_ROWS / 64, 256, 0, stream>>>(qkv_bf, ksum, qp);
  gemm_bt<1><<<1280, 256, 0, stream>>>(qp, gt, out, bproj);
}